// Round 7
// baseline (376.026 us; speedup 1.0000x reference)
//
#include <hip/hip_runtime.h>

#define BB 256
#define TT 512
#define CC 128
#define NBLK (BB / 32)      // 8 blocks, 32 batches (2 groups of 16) each
#define EEXP_OFF 4096       // byte offset of bf16 exp(emissions) in d_ws

typedef short short8 __attribute__((ext_vector_type(8)));
typedef float f32x4  __attribute__((ext_vector_type(4)));

__device__ __forceinline__ unsigned cvtpk(float lo, float hi) {  // bf16(lo)|bf16(hi)<<16
    unsigned r;
    asm("v_cvt_pk_bf16_f32 %0, %1, %2" : "=v"(r) : "v"(lo), "v"(hi));
    return r;
}
__device__ __forceinline__ unsigned umx(unsigned a, unsigned b) { return a > b ? a : b; }
__device__ __forceinline__ f32x4 expv4(f32x4 x) {
    return f32x4{__expf(x[0]), __expf(x[1]), __expf(x[2]), __expf(x[3])};
}
__device__ __forceinline__ float bflo(unsigned u) { return __uint_as_float(u << 16); }
__device__ __forceinline__ float bfhi(unsigned u) { return __uint_as_float(u & 0xFFFF0000u); }

// raw emission regs: PRE -> bf16x8 (2 u32 pairs), else f32x8
template<bool PRE> struct ERaw { uint2 a, b; };
template<> struct ERaw<false> { f32x4 a, b; };

template<bool PRE>
__device__ __forceinline__ ERaw<PRE> eload(const void* base, int idx) {
    if constexpr (PRE) {
        const unsigned short* p = (const unsigned short*)base;
        ERaw<PRE> r;
        r.a = *(const uint2*)&p[idx];
        r.b = *(const uint2*)&p[idx + 16];
        return r;
    } else {
        const float* p = (const float*)base;
        ERaw<PRE> r;
        r.a = *(const f32x4*)&p[idx];
        r.b = *(const f32x4*)&p[idx + 16];
        return r;
    }
}
template<bool PRE>
__device__ __forceinline__ void econv(const ERaw<PRE>& r, f32x4& e0, f32x4& e1) {
    if constexpr (PRE) {
        e0 = f32x4{bflo(r.a.x), bfhi(r.a.x), bflo(r.a.y), bfhi(r.a.y)};
        e1 = f32x4{bflo(r.b.x), bfhi(r.b.x), bflo(r.b.y), bfhi(r.b.y)};
    } else {
        e0 = expv4(r.a);
        e1 = expv4(r.b);
    }
}

// One-time exp(emissions) -> bf16, all CUs, memory-bound (~25us).
__global__ __launch_bounds__(256)
void crf_expemit(const float* __restrict__ em, unsigned short* __restrict__ ee)
{
    const int i = (blockIdx.x * 256 + threadIdx.x) * 8;
    const f32x4 a = *(const f32x4*)&em[i];
    const f32x4 b = *(const f32x4*)&em[i + 4];
    uint4 o;
    o.x = cvtpk(__expf(a[0]), __expf(a[1]));
    o.y = cvtpk(__expf(a[2]), __expf(a[3]));
    o.z = cvtpk(__expf(b[0]), __expf(b[1]));
    o.w = cvtpk(__expf(b[2]), __expf(b[3]));
    *(uint4*)&ee[i] = o;
}

// Forward algorithm, exp domain, MFMA. 8 blocks x 4 waves; each wave carries
// TWO independent 16-batch groups (A,B) through the same instruction stream:
// A's ds_read/MFMA latency hides under B's VALU and vice versa. E^T fragments
// shared (batch-independent). One raw lgkmcnt+s_barrier per step; vmcnt never
// drained, so emission prefetches stay in flight across barriers.
template<bool PRE>
__global__ __launch_bounds__(256, 1)
void crf_forward(const void* __restrict__ em_all,
                 const void* __restrict__ mask,
                 const float* __restrict__ transitions,
                 float* __restrict__ log_den)
{
    const int tid = threadIdx.x;
    const int l = tid & 63, w = tid >> 6;
    const int n = l & 15, g = l >> 4;
    const int bbase = blockIdx.x * 32;      // group A: +n, group B: +16+n

    __shared__ __align__(16) unsigned abuf[2][2][16 * 64]; // [buf][grp] bf16 alpha
    __shared__ float finred[2][4][16];
    __shared__ int lenred[4];

    // u32 index of (batch nn, state s), XOR-swizzled
    auto aidx = [](int nn, int s) -> int {
        return nn * 64 + ((s ^ ((nn & 15) << 3)) >> 1);
    };

    // ---- mask dtype + per-batch lengths for both groups ----
    const unsigned char* mb = (const unsigned char*)mask;
    const bool is_u8 = (mb[1] != 0);    // lengths >= 256 so mask[0][1] is set
    int lenA = 0, lenB = 0;
    #pragma unroll
    for (int grp = 0; grp < 2; ++grp) {
        int cnt = 0;
        const int rowbase = (bbase + 16 * grp + n) * TT + g * 128;
        if (is_u8) {
            const uint4* mp = (const uint4*)(mb + rowbase);
            #pragma unroll
            for (int k = 0; k < 8; ++k) {
                const uint4 v = mp[k];
                const unsigned s4 = (v.x & 0x01010101u) + (v.y & 0x01010101u)
                                  + (v.z & 0x01010101u) + (v.w & 0x01010101u);
                cnt += (int)((s4 * 0x01010101u) >> 24);
            }
        } else {
            const uint4* mp = (const uint4*)((const unsigned*)mask + rowbase);
            #pragma unroll
            for (int k = 0; k < 32; ++k) {
                const uint4 v = mp[k];
                cnt += (v.x ? 1 : 0) + (v.y ? 1 : 0) + (v.z ? 1 : 0) + (v.w ? 1 : 0);
            }
        }
        cnt += __shfl_xor(cnt, 16); cnt += __shfl_xor(cnt, 32);
        if (grp == 0) lenA = cnt; else lenB = cnt;
    }
    int lmx = max(lenA, lenB);
    #pragma unroll
    for (int off = 1; off <= 8; off <<= 1) lmx = max(lmx, __shfl_xor(lmx, off));
    if (l == 0) lenred[w] = lmx;
    __syncthreads();
    const int len_max = max(max(lenred[0], lenred[1]), max(lenred[2], lenred[3]));

    // ---- A-fragments (shared by both groups): A[m,k] = exp(T[k][m]) ----
    short8 afr[2][4];
    #pragma unroll
    for (int mt = 0; mt < 2; ++mt) {
        #pragma unroll
        for (int kt = 0; kt < 4; ++kt) {
            short8 a;
            #pragma unroll
            for (int e = 0; e < 4; ++e) {
                const int k = 32 * kt + 8 * g + 2 * e;
                const int m = 32 * w + 16 * mt + n;
                const unsigned pk2 = cvtpk(__expf(transitions[k * CC + m]),
                                           __expf(transitions[(k + 1) * CC + m]));
                a[2 * e]     = (short)(pk2 & 0xFFFF);
                a[2 * e + 1] = (short)(pk2 >> 16);
            }
            afr[mt][kt] = a;
        }
    }

    const int s0 = 32 * w + 4 * g;         // lane's first state (mt=0); mt=1 at +16
    const size_t strideB = (size_t)TT * CC;
    const void* embA; const void* embB;
    if constexpr (PRE) {
        embA = (const void*)((const unsigned short*)em_all + (size_t)(bbase + n) * strideB);
        embB = (const void*)((const unsigned short*)em_all + (size_t)(bbase + 16 + n) * strideB);
    } else {
        embA = (const void*)((const float*)em_all + (size_t)(bbase + n) * strideB);
        embB = (const void*)((const float*)em_all + (size_t)(bbase + 16 + n) * strideB);
    }

    // ---- t=0 init + emission queue: ec = e[1] (f32), raw = em[2] ----
    float avA[8], avB[8]; unsigned pkA[4], pkB[4];
    {
        f32x4 i0, i1;
        ERaw<PRE> r0 = eload<PRE>(embA, 0 * CC + s0);
        econv<PRE>(r0, i0, i1);
        if constexpr (!PRE) { /* econv already exp'd */ }
        #pragma unroll
        for (int i = 0; i < 4; ++i) { avA[i] = i0[i]; avA[4 + i] = i1[i]; }
        r0 = eload<PRE>(embB, 0 * CC + s0);
        econv<PRE>(r0, i0, i1);
        #pragma unroll
        for (int i = 0; i < 4; ++i) { avB[i] = i0[i]; avB[4 + i] = i1[i]; }
    }
    pkA[0] = cvtpk(avA[0], avA[1]); pkA[1] = cvtpk(avA[2], avA[3]);
    pkA[2] = cvtpk(avA[4], avA[5]); pkA[3] = cvtpk(avA[6], avA[7]);
    pkB[0] = cvtpk(avB[0], avB[1]); pkB[1] = cvtpk(avB[2], avB[3]);
    pkB[2] = cvtpk(avB[4], avB[5]); pkB[3] = cvtpk(avB[6], avB[7]);
    *(uint2*)&abuf[0][0][aidx(n, s0)]      = make_uint2(pkA[0], pkA[1]);
    *(uint2*)&abuf[0][0][aidx(n, s0 + 16)] = make_uint2(pkA[2], pkA[3]);
    *(uint2*)&abuf[0][1][aidx(n, s0)]      = make_uint2(pkB[0], pkB[1]);
    *(uint2*)&abuf[0][1][aidx(n, s0 + 16)] = make_uint2(pkB[2], pkB[3]);

    f32x4 ecA0, ecA1, ecB0, ecB1;
    {
        ERaw<PRE> r1 = eload<PRE>(embA, 1 * CC + s0);
        econv<PRE>(r1, ecA0, ecA1);
        r1 = eload<PRE>(embB, 1 * CC + s0);
        econv<PRE>(r1, ecB0, ecB1);
    }
    ERaw<PRE> rawA = eload<PRE>(embA, ((2 < TT) ? 2 : TT - 1) * CC + s0);
    ERaw<PRE> rawB = eload<PRE>(embB, ((2 < TT) ? 2 : TT - 1) * CC + s0);
    float logoffA = 0.f, logoffB = 0.f;

    __syncthreads();

    for (int t = 1; t < len_max; ++t) {
        // issue emission loads for t+2 (consumed next iteration)
        const int tf = (t + 2 < TT) ? (t + 2) : (TT - 1);
        const ERaw<PRE> ldA = eload<PRE>(embA, tf * CC + s0);
        const ERaw<PRE> ldB = eload<PRE>(embB, tf * CC + s0);

        // B-fragments for both groups from buf[(t+1)&1]
        const unsigned* rbA = abuf[(t + 1) & 1][0];
        const unsigned* rbB = abuf[(t + 1) & 1][1];
        uint4 rA[4], rB[4];
        #pragma unroll
        for (int kt = 0; kt < 4; ++kt) rA[kt] = *(const uint4*)&rbA[aidx(n, 32 * kt + 8 * g)];
        #pragma unroll
        for (int kt = 0; kt < 4; ++kt) rB[kt] = *(const uint4*)&rbB[aidx(n, 32 * kt + 8 * g)];

        f32x4 aA0 = {0,0,0,0}, aA1 = {0,0,0,0}, aB0 = {0,0,0,0}, aB1 = {0,0,0,0};
        #pragma unroll
        for (int kt = 0; kt < 4; ++kt) {
            const short8 bfA = __builtin_bit_cast(short8, rA[kt]);
            const short8 bfB = __builtin_bit_cast(short8, rB[kt]);
            aA0 = __builtin_amdgcn_mfma_f32_16x16x32_bf16(afr[0][kt], bfA, aA0, 0, 0, 0);
            aA1 = __builtin_amdgcn_mfma_f32_16x16x32_bf16(afr[1][kt], bfA, aA1, 0, 0, 0);
            aB0 = __builtin_amdgcn_mfma_f32_16x16x32_bf16(afr[0][kt], bfB, aB0, 0, 0, 0);
            aB1 = __builtin_amdgcn_mfma_f32_16x16x32_bf16(afr[1][kt], bfB, aB1, 0, 0, 0);
        }

        // renorm every 4 steps (exact power-of-2, identical in all waves)
        float scA = 1.0f, scB = 1.0f, exfA = 0.f, exfB = 0.f;
        if ((t & 3) == 0) {
            unsigned mxA = 0, mxB = 0;
            #pragma unroll
            for (int kt = 0; kt < 4; ++kt) {
                mxA = umx(mxA, umx(umx(rA[kt].x & 0xFFFF0000u, rA[kt].x << 16),
                                   umx(rA[kt].y & 0xFFFF0000u, rA[kt].y << 16)));
                mxA = umx(mxA, umx(umx(rA[kt].z & 0xFFFF0000u, rA[kt].z << 16),
                                   umx(rA[kt].w & 0xFFFF0000u, rA[kt].w << 16)));
                mxB = umx(mxB, umx(umx(rB[kt].x & 0xFFFF0000u, rB[kt].x << 16),
                                   umx(rB[kt].y & 0xFFFF0000u, rB[kt].y << 16)));
                mxB = umx(mxB, umx(umx(rB[kt].z & 0xFFFF0000u, rB[kt].z << 16),
                                   umx(rB[kt].w & 0xFFFF0000u, rB[kt].w << 16)));
            }
            mxA = umx(mxA, (unsigned)__shfl_xor((int)mxA, 16));
            mxA = umx(mxA, (unsigned)__shfl_xor((int)mxA, 32));
            mxB = umx(mxB, (unsigned)__shfl_xor((int)mxB, 16));
            mxB = umx(mxB, (unsigned)__shfl_xor((int)mxB, 32));
            const int exA = (int)((mxA >> 23) & 255u) - 127;
            const int exB = (int)((mxB >> 23) & 255u) - 127;
            scA = __uint_as_float((unsigned)(127 - exA) << 23);
            scB = __uint_as_float((unsigned)(127 - exB) << 23);
            exfA = (float)exA; exfB = (float)exB;
        }

        // epilogues (branch-free freeze)
        const bool actA = (t < lenA), actB = (t < lenB);
        float nvA[8], nvB[8];
        #pragma unroll
        for (int i = 0; i < 4; ++i) {
            nvA[i]     = aA0[i] * ecA0[i] * scA;
            nvA[4 + i] = aA1[i] * ecA1[i] * scA;
            nvB[i]     = aB0[i] * ecB0[i] * scB;
            nvB[4 + i] = aB1[i] * ecB1[i] * scB;
        }
        #pragma unroll
        for (int i = 0; i < 8; ++i) {
            avA[i] = actA ? nvA[i] : avA[i];
            avB[i] = actB ? nvB[i] : avB[i];
        }
        unsigned npA[4], npB[4];
        npA[0] = cvtpk(nvA[0], nvA[1]); npA[1] = cvtpk(nvA[2], nvA[3]);
        npA[2] = cvtpk(nvA[4], nvA[5]); npA[3] = cvtpk(nvA[6], nvA[7]);
        npB[0] = cvtpk(nvB[0], nvB[1]); npB[1] = cvtpk(nvB[2], nvB[3]);
        npB[2] = cvtpk(nvB[4], nvB[5]); npB[3] = cvtpk(nvB[6], nvB[7]);
        #pragma unroll
        for (int i = 0; i < 4; ++i) {
            pkA[i] = actA ? npA[i] : pkA[i];
            pkB[i] = actB ? npB[i] : pkB[i];
        }
        logoffA += actA ? exfA * 0.6931471805599453f : 0.f;
        logoffB += actB ? exfB * 0.6931471805599453f : 0.f;

        // shift emission queues
        econv<PRE>(rawA, ecA0, ecA1);
        econv<PRE>(rawB, ecB0, ecB1);
        rawA = ldA; rawB = ldB;

        // publish alpha for t+1
        unsigned* wbA = abuf[t & 1][0];
        unsigned* wbB = abuf[t & 1][1];
        *(uint2*)&wbA[aidx(n, s0)]      = make_uint2(pkA[0], pkA[1]);
        *(uint2*)&wbA[aidx(n, s0 + 16)] = make_uint2(pkA[2], pkA[3]);
        *(uint2*)&wbB[aidx(n, s0)]      = make_uint2(pkB[0], pkB[1]);
        *(uint2*)&wbB[aidx(n, s0 + 16)] = make_uint2(pkB[2], pkB[3]);

        asm volatile("s_waitcnt lgkmcnt(0)\n\ts_barrier" ::: "memory");
    }

    // ---- log_den = logoff + log(sum over states) per group ----
    float sA = ((avA[0] + avA[1]) + (avA[2] + avA[3])) + ((avA[4] + avA[5]) + (avA[6] + avA[7]));
    float sB = ((avB[0] + avB[1]) + (avB[2] + avB[3])) + ((avB[4] + avB[5]) + (avB[6] + avB[7]));
    sA += __shfl_xor(sA, 16); sA += __shfl_xor(sA, 32);
    sB += __shfl_xor(sB, 16); sB += __shfl_xor(sB, 32);
    __syncthreads();
    if (l < 16) { finred[0][w][l] = sA; finred[1][w][l] = sB; }
    __syncthreads();
    if (w == 0 && l < 16) {
        const float tot = finred[0][0][l] + finred[0][1][l] + finred[0][2][l] + finred[0][3][l];
        log_den[bbase + l] = logoffA + __logf(tot);
    }
    if (w == 1 && l < 16) {
        const float tot = finred[1][0][l] + finred[1][1][l] + finred[1][2][l] + finred[1][3][l];
        // logoffB is uniform across waves for a given l (computed from identical data)
        log_den[bbase + 16 + l] = logoffB + __logf(tot);
    }
}

__device__ __forceinline__ bool mask_at(const void* mask, bool is_u8, int idx) {
    if (is_u8) return ((const unsigned char*)mask)[idx] != 0;
    return ((const int*)mask)[idx] != 0;
}

// Gold-path score: sum of masked emissions at tags + masked pair transitions.
__global__ __launch_bounds__(256)
void crf_num(const float* __restrict__ em_all,
             const int* __restrict__ tags,
             const void* __restrict__ mask,
             const float* __restrict__ transitions,
             float* __restrict__ log_num)
{
    const int b = blockIdx.x;
    const int j = threadIdx.x;
    const int lane = j & 63;
    const int wid = j >> 6;
    __shared__ float redf[4];

    const unsigned char* mb = (const unsigned char*)mask;
    const bool is_u8 = (mb[1] != 0);

    const float* em = em_all + (size_t)b * TT * CC;
    const int* tg = tags + b * TT;

    float s = 0.f;
    for (int t = j; t < TT; t += 256) {
        if (mask_at(mask, is_u8, b * TT + t)) {
            s += em[t * CC + tg[t]];
            if (t >= 1 && mask_at(mask, is_u8, b * TT + t - 1))
                s += transitions[tg[t - 1] * CC + tg[t]];
        }
    }
    #pragma unroll
    for (int off = 32; off; off >>= 1) s += __shfl_xor(s, off);
    if (lane == 0) redf[wid] = s;
    __syncthreads();
    if (j == 0) log_num[b] = redf[0] + redf[1] + redf[2] + redf[3];
}

__global__ __launch_bounds__(256)
void crf_final(const float* __restrict__ log_den,
               const float* __restrict__ log_num,
               float* __restrict__ out)
{
    const int j = threadIdx.x;   // one thread per batch, B == 256
    const int lane = j & 63;
    const int wid = j >> 6;
    __shared__ float redf[4];
    float v = log_den[j] - log_num[j];
    #pragma unroll
    for (int off = 32; off; off >>= 1) v += __shfl_xor(v, off);
    if (lane == 0) redf[wid] = v;
    __syncthreads();
    if (j == 0) out[0] = (redf[0] + redf[1] + redf[2] + redf[3]) * (1.0f / BB);
}

extern "C" void kernel_launch(void* const* d_in, const int* in_sizes, int n_in,
                              void* d_out, int out_size, void* d_ws, size_t ws_size,
                              hipStream_t stream) {
    const float* emissions   = (const float*)d_in[0];
    const int*   tags        = (const int*)d_in[1];
    const void*  mask        = d_in[2];
    const float* transitions = (const float*)d_in[3];
    float* out = (float*)d_out;

    float* log_den = (float*)d_ws;
    float* log_num = log_den + BB;

    const size_t eexp_bytes = (size_t)BB * TT * CC * 2;
    const bool pre = ws_size >= (size_t)EEXP_OFF + eexp_bytes;

    if (pre) {
        unsigned short* eexp = (unsigned short*)((char*)d_ws + EEXP_OFF);
        crf_expemit<<<(BB * TT * CC) / 2048, 256, 0, stream>>>(emissions, eexp);
        crf_forward<true><<<NBLK, 256, 0, stream>>>(eexp, mask, transitions, log_den);
    } else {
        crf_forward<false><<<NBLK, 256, 0, stream>>>(emissions, mask, transitions, log_den);
    }
    crf_num<<<BB, 256, 0, stream>>>(emissions, tags, mask, transitions, log_num);
    crf_final<<<1, 256, 0, stream>>>(log_den, log_num, out);
}